// Round 1
// baseline (490.556 us; speedup 1.0000x reference)
//
#include <hip/hip_runtime.h>
#include <stdint.h>

#define BATCH 8
#define SEQ   1025
#define HDIM  1152
#define NH    12
#define DH    96
#define MROWS (BATCH*SEQ)   // 8200
#define N_QKV (3*HDIM)      // 3456
#define KD    HDIM          // 1152 (K of both GEMMs)
#define SPAD  1056          // padded seq for Vt (33 tiles of 32)

typedef __attribute__((ext_vector_type(8))) short short8;
typedef __attribute__((ext_vector_type(4))) short short4_;
typedef __attribute__((ext_vector_type(4))) float float4_;

__device__ inline float bf2f(short s) {
  union { unsigned u; float f; } x; x.u = ((unsigned)(unsigned short)s) << 16; return x.f;
}
__device__ inline short f2bf(float f) {
  union { float f; unsigned u; } x; x.f = f;
  unsigned r = (x.u + 0x7fffu + ((x.u >> 16) & 1u)) >> 16;
  return (short)r;
}

// ---------------- converts ----------------
__global__ __launch_bounds__(256) void convx(const float* __restrict__ hs, short* __restrict__ X) {
  int i = blockIdx.x * 256 + threadIdx.x;  // exactly 2361600 threads
  float4_ v = ((const float4_*)hs)[i];
  short4_ o;
  o[0] = f2bf(v[0]); o[1] = f2bf(v[1]); o[2] = f2bf(v[2]); o[3] = f2bf(v[3]);
  ((short4_*)X)[i] = o;
}

__global__ __launch_bounds__(256) void convw_qkv(const float* __restrict__ Wq,
                                                 const float* __restrict__ Wk,
                                                 const float* __restrict__ Wv,
                                                 short* __restrict__ Wt) {
  long e = (long)blockIdx.x * 256 + threadIdx.x;  // exactly 3456*1152
  int n = (int)(e / KD), k = (int)(e % KD);
  const float* W = n < HDIM ? Wq : (n < 2 * HDIM ? Wk : Wv);
  int nn = n < HDIM ? n : (n < 2 * HDIM ? n - HDIM : n - 2 * HDIM);
  Wt[e] = f2bf(W[(long)k * HDIM + nn]);
}

__global__ __launch_bounds__(256) void convw_o(const float* __restrict__ Wo, short* __restrict__ Wot) {
  long e = (long)blockIdx.x * 256 + threadIdx.x;  // exactly 1152*1152
  int n = (int)(e / HDIM), k = (int)(e % HDIM);
  Wot[e] = f2bf(Wo[(long)k * HDIM + n]);
}

// ---------------- GEMM: C[M][N] = A[M][K] * Bt[N][K]^T + bias ----------------
// m97 structure: 128x128 tile, BK=32, 4 waves (2x2 of 64x64), global_load_lds w16.
template<int OUTF32>
__global__ __launch_bounds__(256, 2) void gemm_kernel(
    const short* __restrict__ A, const short* __restrict__ Bt,
    const float* __restrict__ b0, const float* __restrict__ b1, const float* __restrict__ b2,
    void* __restrict__ Cout, const int N) {
  __shared__ short As[4096];   // [128][32] bf16
  __shared__ short Bs[4096];   // [128][32] bf16 (rows are N-cols)
  const int tid = threadIdx.x;
  const int l = tid & 63, w = tid >> 6;
  const int lrow = l & 15, lg = l >> 4;
  const int n0 = blockIdx.x * 128, m0 = blockIdx.y * 128;
  const int wm = (w >> 1) * 64, wn = (w & 1) * 64;

  float4_ acc[4][4];
#pragma unroll
  for (int i = 0; i < 4; ++i)
#pragma unroll
    for (int j = 0; j < 4; ++j) acc[i][j] = (float4_)(0.f);

  // staging: thread t covers 8 contiguous k at row t/4 (and +64)
  const int sr = tid >> 2;
  const int sk = (tid & 3) * 8;
  int ra0 = m0 + sr;       if (ra0 > MROWS - 1) ra0 = MROWS - 1;
  int ra1 = m0 + 64 + sr;  if (ra1 > MROWS - 1) ra1 = MROWS - 1;
  const short* pa0 = A + (long)ra0 * KD + sk;
  const short* pa1 = A + (long)ra1 * KD + sk;
  const short* pb0 = Bt + (long)(n0 + sr) * KD + sk;
  const short* pb1 = Bt + (long)(n0 + 64 + sr) * KD + sk;
  short* la0 = &As[w * 512];
  short* la1 = &As[2048 + w * 512];
  short* lb0 = &Bs[w * 512];
  short* lb1 = &Bs[2048 + w * 512];

  for (int kt = 0; kt < KD / 32; ++kt) {
    __syncthreads();
    const int ko = kt * 32;
    __builtin_amdgcn_global_load_lds((const __attribute__((address_space(1))) void*)(pa0 + ko),
                                     (__attribute__((address_space(3))) void*)la0, 16, 0, 0);
    __builtin_amdgcn_global_load_lds((const __attribute__((address_space(1))) void*)(pa1 + ko),
                                     (__attribute__((address_space(3))) void*)la1, 16, 0, 0);
    __builtin_amdgcn_global_load_lds((const __attribute__((address_space(1))) void*)(pb0 + ko),
                                     (__attribute__((address_space(3))) void*)lb0, 16, 0, 0);
    __builtin_amdgcn_global_load_lds((const __attribute__((address_space(1))) void*)(pb1 + ko),
                                     (__attribute__((address_space(3))) void*)lb1, 16, 0, 0);
    __syncthreads();  // compiler drains vmcnt before barrier
    short8 af[4], bf[4];
#pragma unroll
    for (int i = 0; i < 4; ++i) af[i] = *(const short8*)&As[(wm + i * 16 + lrow) * 32 + lg * 8];
#pragma unroll
    for (int j = 0; j < 4; ++j) bf[j] = *(const short8*)&Bs[(wn + j * 16 + lrow) * 32 + lg * 8];
#pragma unroll
    for (int i = 0; i < 4; ++i)
#pragma unroll
      for (int j = 0; j < 4; ++j)
        acc[i][j] = __builtin_amdgcn_mfma_f32_16x16x32_bf16(af[i], bf[j], acc[i][j], 0, 0, 0);
  }

  // epilogue: C row = (l>>4)*4+reg, col = l&15 (m89-verified)
#pragma unroll
  for (int i = 0; i < 4; ++i) {
#pragma unroll
    for (int r = 0; r < 4; ++r) {
      int m = m0 + wm + i * 16 + lg * 4 + r;
      if (m >= MROWS) continue;
#pragma unroll
      for (int j = 0; j < 4; ++j) {
        int n = n0 + wn + j * 16 + lrow;
        float bias = (N == HDIM) ? b0[n]
                                 : (n < HDIM ? b0[n] : (n < 2 * HDIM ? b1[n - HDIM] : b2[n - 2 * HDIM]));
        float v = acc[i][j][r] + bias;
        if (OUTF32) ((float*)Cout)[(long)m * N + n] = v;
        else        ((short*)Cout)[(long)m * N + n] = f2bf(v);
      }
    }
  }
}

// ---------------- rotary (in-place on q,k of QKV) ----------------
__global__ __launch_bounds__(256) void rotary_kernel(short* __restrict__ QKV,
                                                     const int* __restrict__ rowsp,
                                                     const int* __restrict__ colsp) {
  int idx = blockIdx.x * 256 + threadIdx.x;  // exactly 8200*12*32
  int j = idx & 31;
  int t = idx >> 5;
  int h = t % NH;
  int m = t / NH;
  int s = m % SEQ;
  int cols = colsp[0];
  int rws = rowsp[0];
  int off = (SEQ != rws * cols) ? 1 : 0;
  int gid = s - off; if (gid < 0) gid = 0;
  int row = gid / cols, col = gid % cols;
  float invf = exp2f((float)(3 * j) * (-13.287712379549449f / 192.0f));  // 10000^(-3j/192)
  float th = row * invf, ps = col * invf;
  float st, ct, sp, cp;
  __sincosf(th, &st, &ct);
  __sincosf(ps, &sp, &cp);
  short* qp = QKV + (long)m * N_QKV + h * DH + 3 * j;
#pragma unroll
  for (int qk = 0; qk < 2; ++qk) {
    short* p = qp + qk * HDIM;
    float x0 = bf2f(p[0]), x1 = bf2f(p[1]), x2 = bf2f(p[2]);
    float r0 =  cp * x0 + sp * st * x1 + sp * ct * x2;
    float r1 =  ct * x1 - st * x2;
    float r2 = -sp * x0 + cp * st * x1 + cp * ct * x2;
    p[0] = f2bf(r0); p[1] = f2bf(r1); p[2] = f2bf(r2);
  }
}

// ---------------- V transpose: Vt[b,h][d][s] (zero-padded to SPAD) ----------------
__global__ __launch_bounds__(256) void transv_kernel(const short* __restrict__ QKV, short* __restrict__ Vt) {
  __shared__ short T[128][98];  // 98: conflict-free column reads
  int bh = blockIdx.y, scn = blockIdx.x;
  int b = bh / NH, h = bh % NH;
  int s0 = scn * 128;
  for (int e = threadIdx.x; e < 128 * 96; e += 256) {
    int sl = e / 96, d = e % 96;
    int s = s0 + sl;
    short v = 0;
    if (s < SEQ) v = QKV[(long)(b * SEQ + s) * N_QKV + 2 * HDIM + h * DH + d];
    T[sl][d] = v;
  }
  __syncthreads();
  for (int e = threadIdx.x; e < 128 * 96; e += 256) {
    int d = e / 128, sl = e % 128;
    int s = s0 + sl;
    if (s < SPAD) Vt[((long)bh * DH + d) * SPAD + s] = T[sl][d];
  }
}

// ---------------- flash attention ----------------
// block = 4 waves, each wave: 16 q-rows, full 1025 keys, KBLK=32.
__global__ __launch_bounds__(256) void attn_kernel(const short* __restrict__ QKV,
                                                   const short* __restrict__ Vt,
                                                   short* __restrict__ CTX) {
  __shared__ short P_lds[4][512];  // per-wave [16][32] bf16
  const int tid = threadIdx.x;
  const int l = tid & 63, w = tid >> 6;
  const int lrow = l & 15, lg = l >> 4;
  const int qb = blockIdx.x, h = blockIdx.y, b = blockIdx.z;

  int sq = qb * 64 + w * 16 + lrow;
  int sqc = sq > SEQ - 1 ? SEQ - 1 : sq;
  const short* Qb = QKV + (long)(b * SEQ + sqc) * N_QKV + h * DH;
  short8 qf[3];
#pragma unroll
  for (int kk = 0; kk < 3; ++kk) qf[kk] = *(const short8*)(Qb + kk * 32 + lg * 8);

  const short* Kb = QKV + (long)(b * SEQ) * N_QKV + HDIM + h * DH;
  const short* Vb = Vt + ((long)(b * NH + h) * DH) * SPAD;

  float m_r[4], l_r[4];
  float4_ ctx[6];
#pragma unroll
  for (int r = 0; r < 4; ++r) { m_r[r] = -1e30f; l_r[r] = 0.f; }
#pragma unroll
  for (int d = 0; d < 6; ++d) ctx[d] = (float4_)(0.f);

  const float scale = 0.1020620726159658f;  // 96^-0.5

  for (int t = 0; t < 33; ++t) {
    const int k0 = t * 32;
    float4_ sc[2];
#pragma unroll
    for (int f = 0; f < 2; ++f) {
      int key = k0 + f * 16 + lrow;
      int keyc = key > SEQ - 1 ? SEQ - 1 : key;
      const short* Kr = Kb + (long)keyc * N_QKV;
      float4_ c = (float4_)(0.f);
#pragma unroll
      for (int kk = 0; kk < 3; ++kk) {
        short8 kf = *(const short8*)(Kr + kk * 32 + lg * 8);
        c = __builtin_amdgcn_mfma_f32_16x16x32_bf16(qf[kk], kf, c, 0, 0, 0);
      }
      sc[f] = c;
    }
    // scale + mask invalid keys (this lane's key col = k0 + 16f + lrow)
#pragma unroll
    for (int f = 0; f < 2; ++f) {
      bool inval = (k0 + f * 16 + lrow) > SEQ - 1;
#pragma unroll
      for (int r = 0; r < 4; ++r) {
        float v = sc[f][r] * scale;
        sc[f][r] = inval ? -1e30f : v;
      }
    }
    // row max across 16 col-lanes
    float tm[4], ts[4];
#pragma unroll
    for (int r = 0; r < 4; ++r) tm[r] = fmaxf(sc[0][r], sc[1][r]);
#pragma unroll
    for (int mk = 1; mk <= 8; mk <<= 1)
#pragma unroll
      for (int r = 0; r < 4; ++r) tm[r] = fmaxf(tm[r], __shfl_xor(tm[r], mk));
    float alpha[4];
#pragma unroll
    for (int r = 0; r < 4; ++r) {
      float mn = fmaxf(m_r[r], tm[r]);
      alpha[r] = __expf(m_r[r] - mn);
      m_r[r] = mn;
    }
#pragma unroll
    for (int d = 0; d < 6; ++d)
#pragma unroll
      for (int r = 0; r < 4; ++r) ctx[d][r] *= alpha[r];
#pragma unroll
    for (int r = 0; r < 4; ++r) ts[r] = 0.f;
#pragma unroll
    for (int f = 0; f < 2; ++f)
#pragma unroll
      for (int r = 0; r < 4; ++r) {
        float p = __expf(sc[f][r] - m_r[r]);
        sc[f][r] = p;
        ts[r] += p;
      }
#pragma unroll
    for (int mk = 1; mk <= 8; mk <<= 1)
#pragma unroll
      for (int r = 0; r < 4; ++r) ts[r] += __shfl_xor(ts[r], mk);
#pragma unroll
    for (int r = 0; r < 4; ++r) l_r[r] = l_r[r] * alpha[r] + ts[r];

    // P (C-layout) -> LDS -> A-layout fragment. Same-wave DS ops are in-order;
    // compiler inserts the lgkmcnt for the read's result use.
#pragma unroll
    for (int f = 0; f < 2; ++f)
#pragma unroll
      for (int r = 0; r < 4; ++r)
        P_lds[w][(lg * 4 + r) * 32 + f * 16 + lrow] = f2bf(sc[f][r]);
    short8 pf = *(const short8*)&P_lds[w][lrow * 32 + lg * 8];
#pragma unroll
    for (int d = 0; d < 6; ++d) {
      short8 vf = *(const short8*)(Vb + (long)(d * 16 + lrow) * SPAD + k0 + lg * 8);
      ctx[d] = __builtin_amdgcn_mfma_f32_16x16x32_bf16(pf, vf, ctx[d], 0, 0, 0);
    }
  }

  float inv[4];
#pragma unroll
  for (int r = 0; r < 4; ++r) inv[r] = 1.f / l_r[r];
#pragma unroll
  for (int r = 0; r < 4; ++r) {
    int so = qb * 64 + w * 16 + lg * 4 + r;
    if (so < SEQ) {
      short* Crow = CTX + (long)(b * SEQ + so) * HDIM + h * DH;
#pragma unroll
      for (int d = 0; d < 6; ++d) Crow[d * 16 + lrow] = f2bf(ctx[d][r] * inv[r]);
    }
  }
}

extern "C" void kernel_launch(void* const* d_in, const int* in_sizes, int n_in,
                              void* d_out, int out_size, void* d_ws, size_t ws_size,
                              hipStream_t stream) {
  const float* hs = (const float*)d_in[0];
  const float* Wq = (const float*)d_in[1];
  const float* bq = (const float*)d_in[2];
  const float* Wk = (const float*)d_in[3];
  const float* bk = (const float*)d_in[4];
  const float* Wv = (const float*)d_in[5];
  const float* bv = (const float*)d_in[6];
  const float* Wo = (const float*)d_in[7];
  const float* bo = (const float*)d_in[8];
  const int* rows = (const int*)d_in[9];
  const int* cols = (const int*)d_in[10];
  float* out = (float*)d_out;

  char* ws = (char*)d_ws;
  short* X   = (short*)(ws);               // 8200*1152*2      = 18,892,800
  short* Wt  = (short*)(ws + 18892800);    // 3456*1152*2      =  7,962,624
  short* Wot = (short*)(ws + 26855424);    // 1152*1152*2      =  2,654,208
  short* QKV = (short*)(ws + 29509632);    // 8200*3456*2      = 56,678,400
  short* Vt  = (short*)(ws + 86188032);    // 96*96*1056*2     = 19,464,192
  short* CTX = (short*)(ws + 105652224);   // 8200*1152*2      = 18,892,800  (end 124,545,024)

  convx<<<9225, 256, 0, stream>>>(hs, X);
  convw_qkv<<<15552, 256, 0, stream>>>(Wq, Wk, Wv, Wt);
  convw_o<<<5184, 256, 0, stream>>>(Wo, Wot);
  gemm_kernel<0><<<dim3(27, 65), 256, 0, stream>>>(X, Wt, bq, bk, bv, QKV, N_QKV);
  rotary_kernel<<<12300, 256, 0, stream>>>(QKV, rows, cols);
  transv_kernel<<<dim3(9, 96), 256, 0, stream>>>(QKV, Vt);
  attn_kernel<<<dim3(17, 12, 8), 256, 0, stream>>>(QKV, Vt, CTX);
  gemm_kernel<1><<<dim3(9, 65), 256, 0, stream>>>(CTX, Wot, bo, bo, bo, out, HDIM);
}

// Round 2
// 405.948 us; speedup vs baseline: 1.2084x; 1.2084x over previous
//
#include <hip/hip_runtime.h>
#include <stdint.h>

#define BATCH 8
#define SEQ   1025
#define HDIM  1152
#define NH    12
#define DH    96
#define MROWS (BATCH*SEQ)   // 8200
#define N_QKV (3*HDIM)      // 3456
#define KD    HDIM          // 1152 (K of both GEMMs)
#define SPAD  1056          // padded seq for Vt (33 tiles of 32)

typedef __attribute__((ext_vector_type(8))) short short8;
typedef __attribute__((ext_vector_type(4))) short short4_;
typedef __attribute__((ext_vector_type(4))) float float4_;
typedef __attribute__((ext_vector_type(16))) float f32x16;

__device__ inline float bf2f(short s) {
  union { unsigned u; float f; } x; x.u = ((unsigned)(unsigned short)s) << 16; return x.f;
}
__device__ inline short f2bf(float f) {
  union { float f; unsigned u; } x; x.f = f;
  unsigned r = (x.u + 0x7fffu + ((x.u >> 16) & 1u)) >> 16;
  return (short)r;
}

// ---------------- converts ----------------
__global__ __launch_bounds__(256) void convx(const float* __restrict__ hs, short* __restrict__ X) {
  int i = blockIdx.x * 256 + threadIdx.x;  // exactly 2361600 threads
  float4_ v = ((const float4_*)hs)[i];
  short4_ o;
  o[0] = f2bf(v[0]); o[1] = f2bf(v[1]); o[2] = f2bf(v[2]); o[3] = f2bf(v[3]);
  ((short4_*)X)[i] = o;
}

__global__ __launch_bounds__(256) void convw_qkv(const float* __restrict__ Wq,
                                                 const float* __restrict__ Wk,
                                                 const float* __restrict__ Wv,
                                                 short* __restrict__ Wt) {
  long e = (long)blockIdx.x * 256 + threadIdx.x;  // exactly 3456*1152
  int n = (int)(e / KD), k = (int)(e % KD);
  const float* W = n < HDIM ? Wq : (n < 2 * HDIM ? Wk : Wv);
  int nn = n < HDIM ? n : (n < 2 * HDIM ? n - HDIM : n - 2 * HDIM);
  Wt[e] = f2bf(W[(long)k * HDIM + nn]);
}

__global__ __launch_bounds__(256) void convw_o(const float* __restrict__ Wo, short* __restrict__ Wot) {
  long e = (long)blockIdx.x * 256 + threadIdx.x;  // exactly 1152*1152
  int n = (int)(e / HDIM), k = (int)(e % HDIM);
  Wot[e] = f2bf(Wo[(long)k * HDIM + n]);
}

// ---------------- GEMM: C[M][N] = A[M][K] * Bt[N][K]^T + bias ----------------
template<int OUTF32>
__global__ __launch_bounds__(256, 2) void gemm_kernel(
    const short* __restrict__ A, const short* __restrict__ Bt,
    const float* __restrict__ b0, const float* __restrict__ b1, const float* __restrict__ b2,
    void* __restrict__ Cout, const int N) {
  __shared__ short As[4096];   // [128][32] bf16
  __shared__ short Bs[4096];   // [128][32] bf16 (rows are N-cols)
  const int tid = threadIdx.x;
  const int l = tid & 63, w = tid >> 6;
  const int lrow = l & 15, lg = l >> 4;
  const int n0 = blockIdx.x * 128, m0 = blockIdx.y * 128;
  const int wm = (w >> 1) * 64, wn = (w & 1) * 64;

  float4_ acc[4][4];
#pragma unroll
  for (int i = 0; i < 4; ++i)
#pragma unroll
    for (int j = 0; j < 4; ++j) acc[i][j] = (float4_)(0.f);

  const int sr = tid >> 2;
  const int sk = (tid & 3) * 8;
  int ra0 = m0 + sr;       if (ra0 > MROWS - 1) ra0 = MROWS - 1;
  int ra1 = m0 + 64 + sr;  if (ra1 > MROWS - 1) ra1 = MROWS - 1;
  const short* pa0 = A + (long)ra0 * KD + sk;
  const short* pa1 = A + (long)ra1 * KD + sk;
  const short* pb0 = Bt + (long)(n0 + sr) * KD + sk;
  const short* pb1 = Bt + (long)(n0 + 64 + sr) * KD + sk;
  short* la0 = &As[w * 512];
  short* la1 = &As[2048 + w * 512];
  short* lb0 = &Bs[w * 512];
  short* lb1 = &Bs[2048 + w * 512];

  for (int kt = 0; kt < KD / 32; ++kt) {
    __syncthreads();
    const int ko = kt * 32;
    __builtin_amdgcn_global_load_lds((const __attribute__((address_space(1))) void*)(pa0 + ko),
                                     (__attribute__((address_space(3))) void*)la0, 16, 0, 0);
    __builtin_amdgcn_global_load_lds((const __attribute__((address_space(1))) void*)(pa1 + ko),
                                     (__attribute__((address_space(3))) void*)la1, 16, 0, 0);
    __builtin_amdgcn_global_load_lds((const __attribute__((address_space(1))) void*)(pb0 + ko),
                                     (__attribute__((address_space(3))) void*)lb0, 16, 0, 0);
    __builtin_amdgcn_global_load_lds((const __attribute__((address_space(1))) void*)(pb1 + ko),
                                     (__attribute__((address_space(3))) void*)lb1, 16, 0, 0);
    __syncthreads();
    short8 af[4], bf[4];
#pragma unroll
    for (int i = 0; i < 4; ++i) af[i] = *(const short8*)&As[(wm + i * 16 + lrow) * 32 + lg * 8];
#pragma unroll
    for (int j = 0; j < 4; ++j) bf[j] = *(const short8*)&Bs[(wn + j * 16 + lrow) * 32 + lg * 8];
#pragma unroll
    for (int i = 0; i < 4; ++i)
#pragma unroll
      for (int j = 0; j < 4; ++j)
        acc[i][j] = __builtin_amdgcn_mfma_f32_16x16x32_bf16(af[i], bf[j], acc[i][j], 0, 0, 0);
  }

#pragma unroll
  for (int i = 0; i < 4; ++i) {
#pragma unroll
    for (int r = 0; r < 4; ++r) {
      int m = m0 + wm + i * 16 + lg * 4 + r;
      if (m >= MROWS) continue;
#pragma unroll
      for (int j = 0; j < 4; ++j) {
        int n = n0 + wn + j * 16 + lrow;
        float bias = (N == HDIM) ? b0[n]
                                 : (n < HDIM ? b0[n] : (n < 2 * HDIM ? b1[n - HDIM] : b2[n - 2 * HDIM]));
        float v = acc[i][j][r] + bias;
        if (OUTF32) ((float*)Cout)[(long)m * N + n] = v;
        else        ((short*)Cout)[(long)m * N + n] = f2bf(v);
      }
    }
  }
}

// ---------------- rotary (in-place on q,k of QKV) ----------------
__global__ __launch_bounds__(256) void rotary_kernel(short* __restrict__ QKV,
                                                     const int* __restrict__ rowsp,
                                                     const int* __restrict__ colsp) {
  int idx = blockIdx.x * 256 + threadIdx.x;  // exactly 8200*12*32
  int j = idx & 31;
  int t = idx >> 5;
  int h = t % NH;
  int m = t / NH;
  int s = m % SEQ;
  int cols = colsp[0];
  int rws = rowsp[0];
  int off = (SEQ != rws * cols) ? 1 : 0;
  int gid = s - off; if (gid < 0) gid = 0;
  int row = gid / cols, col = gid % cols;
  float invf = exp2f((float)(3 * j) * (-13.287712379549449f / 192.0f));  // 10000^(-3j/192)
  float th = row * invf, ps = col * invf;
  float st, ct, sp, cp;
  __sincosf(th, &st, &ct);
  __sincosf(ps, &sp, &cp);
  short* qp = QKV + (long)m * N_QKV + h * DH + 3 * j;
#pragma unroll
  for (int qk = 0; qk < 2; ++qk) {
    short* p = qp + qk * HDIM;
    float x0 = bf2f(p[0]), x1 = bf2f(p[1]), x2 = bf2f(p[2]);
    float r0 =  cp * x0 + sp * st * x1 + sp * ct * x2;
    float r1 =  ct * x1 - st * x2;
    float r2 = -sp * x0 + cp * st * x1 + cp * ct * x2;
    p[0] = f2bf(r0); p[1] = f2bf(r1); p[2] = f2bf(r2);
  }
}

// ---------------- V transpose: Vt[b,h][d][s] (zero-padded to SPAD) ----------------
__global__ __launch_bounds__(256) void transv_kernel(const short* __restrict__ QKV, short* __restrict__ Vt) {
  __shared__ short T[128][98];
  int bh = blockIdx.y, scn = blockIdx.x;
  int b = bh / NH, h = bh % NH;
  int s0 = scn * 128;
  for (int e = threadIdx.x; e < 128 * 96; e += 256) {
    int sl = e / 96, d = e % 96;
    int s = s0 + sl;
    short v = 0;
    if (s < SEQ) v = QKV[(long)(b * SEQ + s) * N_QKV + 2 * HDIM + h * DH + d];
    T[sl][d] = v;
  }
  __syncthreads();
  for (int e = threadIdx.x; e < 128 * 96; e += 256) {
    int d = e / 128, sl = e % 128;
    int s = s0 + sl;
    if (s < SPAD) Vt[((long)bh * DH + d) * SPAD + s] = T[sl][d];
  }
}

// ---------------- flash attention, swapped-operand 32x32 form ----------------
// 2 waves/block, each wave: 32 q-rows (one q per lane-column), all 1025 keys.
// S^T = mfma(K, Q)  -> lane owns q=lane&31, 16 key-rows: lane-local softmax.
// ctx^T = mfma(V^T, P^T) -> accumulator stays one-q-per-lane (scalar rescale).
__global__ __launch_bounds__(128, 3) void attn_kernel(const short* __restrict__ QKV,
                                                      const short* __restrict__ Vt,
                                                      short* __restrict__ CTX) {
  const int tid = threadIdx.x;
  const int l = tid & 63, w = tid >> 6;
  const int qi = l & 31, hi = l >> 5;
  const int h = blockIdx.y, b = blockIdx.z;
  const int s = blockIdx.x * 64 + w * 32 + qi;
  const int sq = s > SEQ - 1 ? SEQ - 1 : s;

  const float scale = 0.1020620726159658f;  // 96^-0.5
  const short* Qr = QKV + (long)(b * SEQ + sq) * N_QKV + h * DH;
  short8 qf[6];  // pre-scaled Q row fragments (B-operand: col=lane&31=q, k=8*hi+j)
#pragma unroll
  for (int c = 0; c < 6; ++c) {
    short8 v = *(const short8*)(Qr + c * 16 + hi * 8);
#pragma unroll
    for (int j = 0; j < 8; ++j) v[j] = f2bf(bf2f(v[j]) * scale);
    qf[c] = v;
  }

  const short* Kb = QKV + (long)(b * SEQ) * N_QKV + HDIM + h * DH;
  const short* Vb = Vt + (long)(b * NH + h) * DH * SPAD;  // [96][SPAD]

  f32x16 ctxv[3];
#pragma unroll
  for (int d = 0; d < 3; ++d) ctxv[d] = (f32x16)(0.f);
  float m_ = -1e30f, l_ = 0.f;

  for (int t = 0; t < 33; ++t) {
    const int k0 = t * 32;
    int krow = k0 + qi; if (krow > SEQ - 1) krow = SEQ - 1;
    const short* Kr = Kb + (long)krow * N_QKV;
    f32x16 S = (f32x16)(0.f);
#pragma unroll
    for (int c = 0; c < 6; ++c) {
      short8 kf = *(const short8*)(Kr + c * 16 + hi * 8);
      S = __builtin_amdgcn_mfma_f32_32x32x16_bf16(kf, qf[c], S, 0, 0, 0);
    }
    if (t == 32) {  // keys 1024..1055: only key 1024 (reg0, hi=0) valid
      S[0] = hi ? -1e30f : S[0];
#pragma unroll
      for (int r = 1; r < 16; ++r) S[r] = -1e30f;
    }
    // lane-local softmax over 16 key-rows + one cross-half combine
    float tm = S[0];
#pragma unroll
    for (int r = 1; r < 16; ++r) tm = fmaxf(tm, S[r]);
    tm = fmaxf(tm, __shfl_xor(tm, 32));
    float mn = fmaxf(m_, tm);
    float alpha = __expf(m_ - mn);
    m_ = mn;
    float ts = 0.f;
#pragma unroll
    for (int r = 0; r < 16; ++r) { float p = __expf(S[r] - mn); S[r] = p; ts += p; }
    ts += __shfl_xor(ts, 32);
    l_ = l_ * alpha + ts;
#pragma unroll
    for (int d = 0; d < 3; ++d)
#pragma unroll
      for (int r = 0; r < 16; ++r) ctxv[d][r] *= alpha;

    // pack P to bf16 pairs; key rows per reg r: (r&3)+8*(r>>2)+4*hi
    unsigned pk_[8];
#pragma unroll
    for (int j = 0; j < 8; ++j)
      pk_[j] = (unsigned)(unsigned short)f2bf(S[2 * j]) |
               ((unsigned)(unsigned short)f2bf(S[2 * j + 1]) << 16);
    // half-exchange so each lane holds its 8 consecutive keys per k-slice
    unsigned s0 = hi ? pk_[0] : pk_[2];
    unsigned s1 = hi ? pk_[1] : pk_[3];
    unsigned s2 = hi ? pk_[4] : pk_[6];
    unsigned s3 = hi ? pk_[5] : pk_[7];
    unsigned r0 = __shfl_xor(s0, 32);
    unsigned r1 = __shfl_xor(s1, 32);
    unsigned r2 = __shfl_xor(s2, 32);
    unsigned r3 = __shfl_xor(s3, 32);
    union PF { unsigned u[4]; short8 s8; } f0, f1;
    f0.u[0] = hi ? r0 : pk_[0];
    f0.u[1] = hi ? r1 : pk_[1];
    f0.u[2] = hi ? pk_[2] : r0;
    f0.u[3] = hi ? pk_[3] : r1;
    f1.u[0] = hi ? r2 : pk_[4];
    f1.u[1] = hi ? r3 : pk_[5];
    f1.u[2] = hi ? pk_[6] : r2;
    f1.u[3] = hi ? pk_[7] : r3;

#pragma unroll
    for (int d = 0; d < 3; ++d) {
      const short* Vr = Vb + (long)(d * 32 + qi) * SPAD + k0;
      short8 vf0 = *(const short8*)(Vr + hi * 8);
      ctxv[d] = __builtin_amdgcn_mfma_f32_32x32x16_bf16(vf0, f0.s8, ctxv[d], 0, 0, 0);
      short8 vf1 = *(const short8*)(Vr + 16 + hi * 8);
      ctxv[d] = __builtin_amdgcn_mfma_f32_32x32x16_bf16(vf1, f1.s8, ctxv[d], 0, 0, 0);
    }
  }

  float invl = 1.f / l_;
  if (s <= SEQ - 1) {
    short* Cr = CTX + (long)(b * SEQ + s) * HDIM + h * DH;
#pragma unroll
    for (int d = 0; d < 3; ++d)
#pragma unroll
      for (int g = 0; g < 4; ++g) {
        short4_ o;
#pragma unroll
        for (int r = 0; r < 4; ++r) o[r] = f2bf(ctxv[d][4 * g + r] * invl);
        *(short4_*)(Cr + d * 32 + 8 * g + 4 * hi) = o;
      }
  }
}

extern "C" void kernel_launch(void* const* d_in, const int* in_sizes, int n_in,
                              void* d_out, int out_size, void* d_ws, size_t ws_size,
                              hipStream_t stream) {
  const float* hs = (const float*)d_in[0];
  const float* Wq = (const float*)d_in[1];
  const float* bq = (const float*)d_in[2];
  const float* Wk = (const float*)d_in[3];
  const float* bk = (const float*)d_in[4];
  const float* Wv = (const float*)d_in[5];
  const float* bv = (const float*)d_in[6];
  const float* Wo = (const float*)d_in[7];
  const float* bo = (const float*)d_in[8];
  const int* rows = (const int*)d_in[9];
  const int* cols = (const int*)d_in[10];
  float* out = (float*)d_out;

  char* ws = (char*)d_ws;
  short* X   = (short*)(ws);               // 8200*1152*2      = 18,892,800
  short* Wt  = (short*)(ws + 18892800);    // 3456*1152*2      =  7,962,624
  short* Wot = (short*)(ws + 26855424);    // 1152*1152*2      =  2,654,208
  short* QKV = (short*)(ws + 29509632);    // 8200*3456*2      = 56,678,400
  short* Vt  = (short*)(ws + 86188032);    // 96*96*1056*2     = 19,464,192
  short* CTX = (short*)(ws + 105652224);   // 8200*1152*2      = 18,892,800  (end 124,545,024)

  convx<<<9225, 256, 0, stream>>>(hs, X);
  convw_qkv<<<15552, 256, 0, stream>>>(Wq, Wk, Wv, Wt);
  convw_o<<<5184, 256, 0, stream>>>(Wo, Wot);
  gemm_kernel<0><<<dim3(27, 65), 256, 0, stream>>>(X, Wt, bq, bk, bv, QKV, N_QKV);
  rotary_kernel<<<12300, 256, 0, stream>>>(QKV, rows, cols);
  transv_kernel<<<dim3(9, 96), 256, 0, stream>>>(QKV, Vt);
  attn_kernel<<<dim3(17, 12, 8), 128, 0, stream>>>(QKV, Vt, CTX);
  gemm_kernel<1><<<dim3(9, 65), 256, 0, stream>>>(CTX, Wot, bo, bo, bo, out, HDIM);
}

// Round 3
// 304.336 us; speedup vs baseline: 1.6119x; 1.3339x over previous
//
#include <hip/hip_runtime.h>
#include <stdint.h>

#define BATCH 8
#define SEQ   1025
#define HDIM  1152
#define NH    12
#define DH    96
#define MROWS (BATCH*SEQ)   // 8200
#define N_QKV (3*HDIM)      // 3456
#define KD    HDIM          // 1152 (K of both GEMMs)

typedef __attribute__((ext_vector_type(8))) short short8;
typedef __attribute__((ext_vector_type(4))) short short4_;
typedef __attribute__((ext_vector_type(4))) float float4_;
typedef __attribute__((ext_vector_type(16))) float f32x16;

__device__ inline float bf2f(short s) {
  union { unsigned u; float f; } x; x.u = ((unsigned)(unsigned short)s) << 16; return x.f;
}
__device__ inline short f2bf(float f) {
  union { float f; unsigned u; } x; x.f = f;
  unsigned r = (x.u + 0x7fffu + ((x.u >> 16) & 1u)) >> 16;
  return (short)r;
}

// ---------------- converts ----------------
__global__ __launch_bounds__(256) void convx(const float* __restrict__ hs, short* __restrict__ X) {
  int i = blockIdx.x * 256 + threadIdx.x;  // exactly 2361600 threads
  float4_ v = ((const float4_*)hs)[i];
  short4_ o;
  o[0] = f2bf(v[0]); o[1] = f2bf(v[1]); o[2] = f2bf(v[2]); o[3] = f2bf(v[3]);
  ((short4_*)X)[i] = o;
}

__global__ __launch_bounds__(256) void convw_qkv(const float* __restrict__ Wq,
                                                 const float* __restrict__ Wk,
                                                 const float* __restrict__ Wv,
                                                 short* __restrict__ Wt) {
  long e = (long)blockIdx.x * 256 + threadIdx.x;  // exactly 3456*1152
  int n = (int)(e / KD), k = (int)(e % KD);
  const float* W = n < HDIM ? Wq : (n < 2 * HDIM ? Wk : Wv);
  int nn = n < HDIM ? n : (n < 2 * HDIM ? n - HDIM : n - 2 * HDIM);
  Wt[e] = f2bf(W[(long)k * HDIM + nn]);
}

__global__ __launch_bounds__(256) void convw_o(const float* __restrict__ Wo, short* __restrict__ Wot) {
  long e = (long)blockIdx.x * 256 + threadIdx.x;  // exactly 1152*1152
  int n = (int)(e / HDIM), k = (int)(e % HDIM);
  Wot[e] = f2bf(Wo[(long)k * HDIM + n]);
}

// ---------------- GEMM: C[M][N] = A[M][K] * Bt[N][K]^T + bias ----------------
template<int OUTF32>
__global__ __launch_bounds__(256, 2) void gemm_kernel(
    const short* __restrict__ A, const short* __restrict__ Bt,
    const float* __restrict__ b0, const float* __restrict__ b1, const float* __restrict__ b2,
    void* __restrict__ Cout, const int N) {
  __shared__ short As[4096];   // [128][32] bf16
  __shared__ short Bs[4096];   // [128][32] bf16 (rows are N-cols)
  const int tid = threadIdx.x;
  const int l = tid & 63, w = tid >> 6;
  const int lrow = l & 15, lg = l >> 4;
  const int n0 = blockIdx.x * 128, m0 = blockIdx.y * 128;
  const int wm = (w >> 1) * 64, wn = (w & 1) * 64;

  float4_ acc[4][4];
#pragma unroll
  for (int i = 0; i < 4; ++i)
#pragma unroll
    for (int j = 0; j < 4; ++j) acc[i][j] = (float4_)(0.f);

  const int sr = tid >> 2;
  const int sk = (tid & 3) * 8;
  int ra0 = m0 + sr;       if (ra0 > MROWS - 1) ra0 = MROWS - 1;
  int ra1 = m0 + 64 + sr;  if (ra1 > MROWS - 1) ra1 = MROWS - 1;
  const short* pa0 = A + (long)ra0 * KD + sk;
  const short* pa1 = A + (long)ra1 * KD + sk;
  const short* pb0 = Bt + (long)(n0 + sr) * KD + sk;
  const short* pb1 = Bt + (long)(n0 + 64 + sr) * KD + sk;
  short* la0 = &As[w * 512];
  short* la1 = &As[2048 + w * 512];
  short* lb0 = &Bs[w * 512];
  short* lb1 = &Bs[2048 + w * 512];

  for (int kt = 0; kt < KD / 32; ++kt) {
    __syncthreads();
    const int ko = kt * 32;
    __builtin_amdgcn_global_load_lds((const __attribute__((address_space(1))) void*)(pa0 + ko),
                                     (__attribute__((address_space(3))) void*)la0, 16, 0, 0);
    __builtin_amdgcn_global_load_lds((const __attribute__((address_space(1))) void*)(pa1 + ko),
                                     (__attribute__((address_space(3))) void*)la1, 16, 0, 0);
    __builtin_amdgcn_global_load_lds((const __attribute__((address_space(1))) void*)(pb0 + ko),
                                     (__attribute__((address_space(3))) void*)lb0, 16, 0, 0);
    __builtin_amdgcn_global_load_lds((const __attribute__((address_space(1))) void*)(pb1 + ko),
                                     (__attribute__((address_space(3))) void*)lb1, 16, 0, 0);
    __syncthreads();
    short8 af[4], bf[4];
#pragma unroll
    for (int i = 0; i < 4; ++i) af[i] = *(const short8*)&As[(wm + i * 16 + lrow) * 32 + lg * 8];
#pragma unroll
    for (int j = 0; j < 4; ++j) bf[j] = *(const short8*)&Bs[(wn + j * 16 + lrow) * 32 + lg * 8];
#pragma unroll
    for (int i = 0; i < 4; ++i)
#pragma unroll
      for (int j = 0; j < 4; ++j)
        acc[i][j] = __builtin_amdgcn_mfma_f32_16x16x32_bf16(af[i], bf[j], acc[i][j], 0, 0, 0);
  }

#pragma unroll
  for (int i = 0; i < 4; ++i) {
#pragma unroll
    for (int r = 0; r < 4; ++r) {
      int m = m0 + wm + i * 16 + lg * 4 + r;
      if (m >= MROWS) continue;
#pragma unroll
      for (int j = 0; j < 4; ++j) {
        int n = n0 + wn + j * 16 + lrow;
        float bias = (N == HDIM) ? b0[n]
                                 : (n < HDIM ? b0[n] : (n < 2 * HDIM ? b1[n - HDIM] : b2[n - 2 * HDIM]));
        float v = acc[i][j][r] + bias;
        if (OUTF32) ((float*)Cout)[(long)m * N + n] = v;
        else        ((short*)Cout)[(long)m * N + n] = f2bf(v);
      }
    }
  }
}

// ---------------- rotary (in-place on q,k of QKV) ----------------
__global__ __launch_bounds__(256) void rotary_kernel(short* __restrict__ QKV,
                                                     const int* __restrict__ rowsp,
                                                     const int* __restrict__ colsp) {
  int idx = blockIdx.x * 256 + threadIdx.x;  // exactly 8200*12*32
  int j = idx & 31;
  int t = idx >> 5;
  int h = t % NH;
  int m = t / NH;
  int s = m % SEQ;
  int cols = colsp[0];
  int rws = rowsp[0];
  int off = (SEQ != rws * cols) ? 1 : 0;
  int gid = s - off; if (gid < 0) gid = 0;
  int row = gid / cols, col = gid % cols;
  float invf = exp2f((float)(3 * j) * (-13.287712379549449f / 192.0f));  // 10000^(-3j/192)
  float th = row * invf, ps = col * invf;
  float st, ct, sp, cp;
  __sincosf(th, &st, &ct);
  __sincosf(ps, &sp, &cp);
  short* qp = QKV + (long)m * N_QKV + h * DH + 3 * j;
#pragma unroll
  for (int qk = 0; qk < 2; ++qk) {
    short* p = qp + qk * HDIM;
    float x0 = bf2f(p[0]), x1 = bf2f(p[1]), x2 = bf2f(p[2]);
    float r0 =  cp * x0 + sp * st * x1 + sp * ct * x2;
    float r1 =  ct * x1 - st * x2;
    float r2 = -sp * x0 + cp * st * x1 + cp * ct * x2;
    p[0] = f2bf(r0); p[1] = f2bf(r1); p[2] = f2bf(r2);
  }
}

// ---------------- fragment prepack: K and V into per-lane MFMA fragment order ----------------
// Kf[bh][t][c][lane] : lane(qi,hi) holds K[key=t*32+qi][c*16+hi*8 .. +8]   (A-operand of S^T MFMA)
// Vf[bh][t][d][sl][lane] : lane(qi,hi) holds V[key=t*32+sl*16+hi*8+j][dd=d*32+qi] (A-operand of PV)
__global__ __launch_bounds__(256) void fragpack(const short* __restrict__ QKV,
                                                short* __restrict__ Kf,
                                                short* __restrict__ Vf) {
  __shared__ short L[64 * 96];  // [kv=2][row 32][96]
  const int t = blockIdx.x, bh = blockIdx.y;
  const int b = bh / NH, h = bh % NH;
  const int tid = threadIdx.x;
#pragma unroll
  for (int i = 0; i < 3; ++i) {
    int cc = i * 256 + tid;          // 0..767 chunks of 16B
    int kv = cc / 384;               // 0=K, 1=V
    int rm = cc % 384;
    int r = rm / 12, m = rm % 12;
    int s = t * 32 + r; if (s > SEQ - 1) s = SEQ - 1;
    const short* src = QKV + (long)(b * SEQ + s) * N_QKV + (kv ? 2 * HDIM : HDIM) + h * DH + m * 8;
    *(short8*)&L[cc * 8] = *(const short8*)src;
  }
  __syncthreads();
#pragma unroll
  for (int i = 0; i < 3; ++i) {
    int oc = i * 256 + tid;          // 0..767 output fragments
    if (oc < 384) {                  // K fragments: oc = c*64 + l
      int c = oc / 64, l = oc & 63;
      int qi = l & 31, hi = l >> 5;
      short8 v = *(const short8*)&L[qi * 96 + c * 16 + hi * 8];
      *(short8*)(Kf + (((long)(bh * 33 + t) * 6 + c) * 64 + l) * 8) = v;
    } else {                         // V fragments: (oc-384) = d*128 + sl*64 + l
      int oc2 = oc - 384;
      int d = oc2 / 128, sl = (oc2 / 64) & 1, l = oc2 & 63;
      int qi = l & 31, hi = l >> 5;
      short8 v;
#pragma unroll
      for (int j = 0; j < 8; ++j)
        v[j] = L[32 * 96 + (sl * 16 + hi * 8 + j) * 96 + d * 32 + qi];
      *(short8*)(Vf + ((((long)(bh * 33 + t) * 3 + d) * 2 + sl) * 64 + l) * 8) = v;
    }
  }
}

// ---------------- flash attention, swapped-operand 32x32, prepacked K/V ----------------
// 2 waves/block, each wave: 32 q-rows (one q per lane-column), all 1025 keys.
// All K/V loads are coalesced 1KB streams from Kf/Vf; XCD-swizzled so the 17
// q-blocks sharing a (b,h) stream live on one XCD (L2 reuse).
__global__ __launch_bounds__(128, 3) void attn_kernel(const short* __restrict__ QKV,
                                                      const short* __restrict__ Kf,
                                                      const short* __restrict__ Vf,
                                                      short* __restrict__ CTX) {
  const int tid = threadIdx.x;
  const int l = tid & 63, w = tid >> 6;
  const int qi = l & 31, hi = l >> 5;
  // bijective XCD swizzle: 1632 = 8 xcd * (12 pairs * 17 qb)
  const int bid = blockIdx.x;
  const int xcd = bid & 7, jj = bid >> 3;
  const int bh = xcd * 12 + jj / 17;
  const int qb = jj % 17;
  const int b = bh / NH, h = bh % NH;
  const int s = qb * 64 + w * 32 + qi;
  const int sq = s > SEQ - 1 ? SEQ - 1 : s;

  const float scale = 0.1020620726159658f;  // 96^-0.5
  const short* Qr = QKV + (long)(b * SEQ + sq) * N_QKV + h * DH;
  short8 qf[6];  // pre-scaled Q fragments (B-operand: col=qi=q, k=c*16+hi*8+j)
#pragma unroll
  for (int c = 0; c < 6; ++c) {
    short8 v = *(const short8*)(Qr + c * 16 + hi * 8);
#pragma unroll
    for (int j = 0; j < 8; ++j) v[j] = f2bf(bf2f(v[j]) * scale);
    qf[c] = v;
  }

  const short* Kb = Kf + (long)bh * 33 * 6 * 64 * 8;
  const short* Vb = Vf + (long)bh * 33 * 6 * 64 * 8;

  f32x16 ctxv[3];
#pragma unroll
  for (int d = 0; d < 3; ++d) ctxv[d] = (f32x16)(0.f);
  float m_ = -1e30f, l_ = 0.f;

  for (int t = 0; t < 33; ++t) {
    f32x16 S = (f32x16)(0.f);
#pragma unroll
    for (int c = 0; c < 6; ++c) {
      short8 kf = *(const short8*)(Kb + (((long)t * 6 + c) * 64 + l) * 8);
      S = __builtin_amdgcn_mfma_f32_32x32x16_bf16(kf, qf[c], S, 0, 0, 0);
    }
    if (t == 32) {  // keys 1024..1055: only key 1024 (reg0, hi=0) valid
      S[0] = hi ? -1e30f : S[0];
#pragma unroll
      for (int r = 1; r < 16; ++r) S[r] = -1e30f;
    }
    // lane-local max over 16 key-rows + cross-half combine
    float tm = S[0];
#pragma unroll
    for (int r = 1; r < 16; ++r) tm = fmaxf(tm, S[r]);
    tm = fmaxf(tm, __shfl_xor(tm, 32));
    // defer-max (T13): only rescale when max grew by > 8
    if (!__all(tm - m_ <= 8.f)) {
      float mn = fmaxf(m_, tm);
      float alpha = __expf(m_ - mn);
      m_ = mn;
      l_ *= alpha;
#pragma unroll
      for (int d = 0; d < 3; ++d)
#pragma unroll
        for (int r = 0; r < 16; ++r) ctxv[d][r] *= alpha;
    }
    float ts = 0.f;
#pragma unroll
    for (int r = 0; r < 16; ++r) { float p = __expf(S[r] - m_); S[r] = p; ts += p; }
    ts += __shfl_xor(ts, 32);
    l_ += ts;

    // pack P to bf16 pairs; key rows per reg r: (r&3)+8*(r>>2)+4*hi
    unsigned pk_[8];
#pragma unroll
    for (int j = 0; j < 8; ++j)
      pk_[j] = (unsigned)(unsigned short)f2bf(S[2 * j]) |
               ((unsigned)(unsigned short)f2bf(S[2 * j + 1]) << 16);
    // half-exchange so each lane holds its 8 consecutive keys per k-slice
    unsigned s0 = hi ? pk_[0] : pk_[2];
    unsigned s1 = hi ? pk_[1] : pk_[3];
    unsigned s2 = hi ? pk_[4] : pk_[6];
    unsigned s3 = hi ? pk_[5] : pk_[7];
    unsigned r0 = __shfl_xor(s0, 32);
    unsigned r1 = __shfl_xor(s1, 32);
    unsigned r2 = __shfl_xor(s2, 32);
    unsigned r3 = __shfl_xor(s3, 32);
    union PF { unsigned u[4]; short8 s8; } f0, f1;
    f0.u[0] = hi ? r0 : pk_[0];
    f0.u[1] = hi ? r1 : pk_[1];
    f0.u[2] = hi ? pk_[2] : r0;
    f0.u[3] = hi ? pk_[3] : r1;
    f1.u[0] = hi ? r2 : pk_[4];
    f1.u[1] = hi ? r3 : pk_[5];
    f1.u[2] = hi ? pk_[6] : r2;
    f1.u[3] = hi ? pk_[7] : r3;

#pragma unroll
    for (int d = 0; d < 3; ++d) {
      const short* Vr = Vb + (((long)t * 3 + d) * 2 * 64) * 8;
      short8 vf0 = *(const short8*)(Vr + l * 8);
      ctxv[d] = __builtin_amdgcn_mfma_f32_32x32x16_bf16(vf0, f0.s8, ctxv[d], 0, 0, 0);
      short8 vf1 = *(const short8*)(Vr + (64 + l) * 8);
      ctxv[d] = __builtin_amdgcn_mfma_f32_32x32x16_bf16(vf1, f1.s8, ctxv[d], 0, 0, 0);
    }
  }

  float invl = 1.f / l_;
  if (s <= SEQ - 1) {
    short* Cr = CTX + (long)(b * SEQ + s) * HDIM + h * DH;
#pragma unroll
    for (int d = 0; d < 3; ++d)
#pragma unroll
      for (int g = 0; g < 4; ++g) {
        short4_ o;
#pragma unroll
        for (int r = 0; r < 4; ++r) o[r] = f2bf(ctxv[d][4 * g + r] * invl);
        *(short4_*)(Cr + d * 32 + 8 * g + 4 * hi) = o;
      }
  }
}

extern "C" void kernel_launch(void* const* d_in, const int* in_sizes, int n_in,
                              void* d_out, int out_size, void* d_ws, size_t ws_size,
                              hipStream_t stream) {
  const float* hs = (const float*)d_in[0];
  const float* Wq = (const float*)d_in[1];
  const float* bq = (const float*)d_in[2];
  const float* Wk = (const float*)d_in[3];
  const float* bk = (const float*)d_in[4];
  const float* Wv = (const float*)d_in[5];
  const float* bv = (const float*)d_in[6];
  const float* Wo = (const float*)d_in[7];
  const float* bo = (const float*)d_in[8];
  const int* rows = (const int*)d_in[9];
  const int* cols = (const int*)d_in[10];
  float* out = (float*)d_out;

  char* ws = (char*)d_ws;
  short* X   = (short*)(ws);               // 8200*1152*2      = 18,892,800
  short* Wt  = (short*)(ws + 18892800);    // 3456*1152*2      =  7,962,624
  short* Wot = (short*)(ws + 26855424);    // 1152*1152*2      =  2,654,208
  short* QKV = (short*)(ws + 29509632);    // 8200*3456*2      = 56,678,400
  short* Vf  = (short*)(ws + 86188032);    // 96*33*6*64*16B   = 19,464,192
  short* CTX = (short*)(ws + 105652224);   // 8200*1152*2      = 18,892,800  (end 124,545,024)
  short* Kf  = (short*)(ws);               // 19,464,192 — reuses X+Wt region (dead after gemm<0>)

  convx<<<9225, 256, 0, stream>>>(hs, X);
  convw_qkv<<<15552, 256, 0, stream>>>(Wq, Wk, Wv, Wt);
  convw_o<<<5184, 256, 0, stream>>>(Wo, Wot);
  gemm_kernel<0><<<dim3(27, 65), 256, 0, stream>>>(X, Wt, bq, bk, bv, QKV, N_QKV);
  rotary_kernel<<<12300, 256, 0, stream>>>(QKV, rows, cols);
  fragpack<<<dim3(33, 96), 256, 0, stream>>>(QKV, Kf, Vf);
  attn_kernel<<<1632, 128, 0, stream>>>(QKV, Kf, Vf, CTX);
  gemm_kernel<1><<<dim3(9, 65), 256, 0, stream>>>(CTX, Wot, bo, bo, bo, out, HDIM);
}